// Round 6
// baseline (656.415 us; speedup 1.0000x reference)
//
#include <hip/hip_runtime.h>
#include <math.h>

#define EPSF 1e-6f
#define BP_ITERS 7

// ---- d_out layout (float offsets) ----
#define OFF_A    0ull
#define OFF_B1   33554432ull
#define OFF_B2   33882112ull
#define OFF_B3   34209792ull
#define OFF_AF1  34537472ull
#define OFF_AF2  68091904ull
#define OFF_AF3  101646336ull
// scratch parked inside d_out (regions dead until later kernels overwrite them)
#define Y1_OFF  (OFF_AF1)                 // [B][512][64] fp32
#define X1_OFF  (OFF_AF1 + 4194304ull)    // [B][512][64] fp32
#define Y2_OFF  (OFF_AF2)                 // [B][512][32] fp32
#define X2_OFF  (OFF_AF2 + 2097152ull)    // [B][512][32] fp32
#define AT_OFF  (OFF_AF2 + 4194304ull)    // At[b][j(512)][i(256)] = A[b][256+i][j], 16777216 floats
#define PARKB   (OFF_AF2 + 20971520ull)   // bc1/bc2 park: b*64 + {0,32}; overwritten only by k_aff

typedef __attribute__((ext_vector_type(8))) short bf16x8;
typedef __attribute__((ext_vector_type(4))) short s16x4;
typedef __attribute__((ext_vector_type(4))) float f32x4;

__device__ __forceinline__ short f2bf(float f) {
  unsigned u = __float_as_uint(f);
  unsigned r = (u + 0x7fffu + ((u >> 16) & 1u)) >> 16;
  return (short)r;
}
__device__ __forceinline__ float bf2f(short h) {
  return __uint_as_float(((unsigned)(unsigned short)h) << 16);
}

// ---------------- 1. split-bf16 MFMA GEMM: C[b](512xBN) = A[b](512xK) @ B(KxBN) ----------------
// POST: fused rowsum(A-tile-rows) during staging; epilogue relu(acc/(rs+eps)+bias)
template<int BN, bool POST>
__global__ __launch_bounds__(256) void k_mgemm(const float* __restrict__ Ain, size_t astride,
                                               const float* __restrict__ Bin, size_t bstride,
                                               float* __restrict__ Cout,
                                               const float* __restrict__ bias, int K) {
  constexpr int BM = 128, BK = 64, LDA = BK + 8;
  constexpr int NF = BN / 16;
  __shared__ short Ahi[BM * LDA], Alo[BM * LDA];
  __shared__ short Bhi[BN * LDA], Blo[BN * LDA];
  __shared__ float rs[BM];
  __shared__ float bls[BN];
  int b = blockIdx.x >> 2, mt = blockIdx.x & 3;
  int m0 = mt * BM;
  int t = threadIdx.x;
  int w = t >> 6, l = t & 63;
  if constexpr (POST) {
    if (t < BM) rs[t] = 0.f;
    if (t < BN) bls[t] = bias[t];
    __syncthreads();
  }
  const float* Ab = Ain + (size_t)b * astride + (size_t)m0 * K;
  const float* Bb = Bin + (size_t)b * bstride;
  f32x4 acc[2][NF];
  #pragma unroll
  for (int mf = 0; mf < 2; ++mf)
    #pragma unroll
    for (int nf = 0; nf < NF; ++nf) acc[mf][nf] = (f32x4){0.f, 0.f, 0.f, 0.f};

  for (int kt = 0; kt < K; kt += BK) {
    #pragma unroll
    for (int i = 0; i < 8; ++i) {
      int f = (t + i * 256) * 4;
      int r = f >> 6, k = f & 63;
      float4 v = *(const float4*)(Ab + (size_t)r * K + kt + k);
      if constexpr (POST) atomicAdd(&rs[r], v.x + v.y + v.z + v.w);
      float xs[4] = {v.x, v.y, v.z, v.w};
      s16x4 h, lo;
      #pragma unroll
      for (int e = 0; e < 4; ++e) {
        h[e] = f2bf(xs[e]);
        lo[e] = f2bf(xs[e] - bf2f(h[e]));
      }
      *(s16x4*)&Ahi[r * LDA + k] = h;
      *(s16x4*)&Alo[r * LDA + k] = lo;
    }
    #pragma unroll
    for (int i = 0; i < BK * BN / 1024; ++i) {
      int f = (t + i * 256) * 4;
      int k = f / BN, n = f % BN;
      float4 v = *(const float4*)(Bb + (size_t)(kt + k) * BN + n);
      float xs[4] = {v.x, v.y, v.z, v.w};
      #pragma unroll
      for (int e = 0; e < 4; ++e) {
        short h = f2bf(xs[e]);
        Bhi[(n + e) * LDA + k] = h;
        Blo[(n + e) * LDA + k] = f2bf(xs[e] - bf2f(h));
      }
    }
    __syncthreads();
    #pragma unroll
    for (int kc = 0; kc < 2; ++kc) {
      int kb = kc * 32 + (l >> 4) * 8;
      bf16x8 ah[2], al[2];
      #pragma unroll
      for (int mf = 0; mf < 2; ++mf) {
        int row = w * 32 + mf * 16 + (l & 15);
        ah[mf] = *(const bf16x8*)&Ahi[row * LDA + kb];
        al[mf] = *(const bf16x8*)&Alo[row * LDA + kb];
      }
      #pragma unroll
      for (int nf = 0; nf < NF; ++nf) {
        int col = nf * 16 + (l & 15);
        bf16x8 bh = *(const bf16x8*)&Bhi[col * LDA + kb];
        bf16x8 bl = *(const bf16x8*)&Blo[col * LDA + kb];
        #pragma unroll
        for (int mf = 0; mf < 2; ++mf) {
          acc[mf][nf] = __builtin_amdgcn_mfma_f32_16x16x32_bf16(ah[mf], bh, acc[mf][nf], 0, 0, 0);
          acc[mf][nf] = __builtin_amdgcn_mfma_f32_16x16x32_bf16(ah[mf], bl, acc[mf][nf], 0, 0, 0);
          acc[mf][nf] = __builtin_amdgcn_mfma_f32_16x16x32_bf16(al[mf], bh, acc[mf][nf], 0, 0, 0);
        }
      }
    }
    __syncthreads();
  }
  #pragma unroll
  for (int mf = 0; mf < 2; ++mf) {
    #pragma unroll
    for (int nf = 0; nf < NF; ++nf) {
      int col = nf * 16 + (l & 15);
      #pragma unroll
      for (int i = 0; i < 4; ++i) {
        int rloc = w * 32 + mf * 16 + (l >> 4) * 4 + i;
        float x = acc[mf][nf][i];
        if constexpr (POST) x = fmaxf(x / (rs[rloc] + EPSF) + bls[col], 0.f);
        Cout[((size_t)b * 512 + m0 + rloc) * BN + col] = x;
      }
    }
  }
}

// ---------------- 2. binary_comp_calc ----------------
template<int D>
__global__ __launch_bounds__(256) void k_bc(const float* __restrict__ X, const int* __restrict__ labels,
                                            float* __restrict__ dst, int parkoff) {
  constexpr int SL = 256 / D;
  constexpr int NPER = 512 / SL;
  __shared__ int labs[512];
  __shared__ float part[SL * 5 * D];
  __shared__ float cnt[5], nrm[5], proto[5 * D], dots[25];
  int b = blockIdx.x, t = threadIdx.x;
  labs[t] = labels[b * 512 + t];
  labs[t + 256] = labels[b * 512 + 256 + t];
  if (t < 5) { cnt[t] = 0.f; nrm[t] = 0.f; }
  __syncthreads();
  if (t < 128) {
    #pragma unroll
    for (int k = 0; k < 4; ++k) atomicAdd(&cnt[labs[t * 4 + k]], 1.f);
  }
  {
    int s = t / D, d = t % D;
    float a5[5] = {};
    for (int k = 0; k < NPER; ++k) {
      int n = s * NPER + k;
      float x = X[((size_t)b * 512 + n) * D + d];
      int lab = labs[n];
      #pragma unroll
      for (int w = 0; w < 5; ++w) a5[w] += (lab == w) ? x : 0.f;
    }
    #pragma unroll
    for (int w = 0; w < 5; ++w) part[(s * 5 + w) * D + d] = a5[w];
  }
  __syncthreads();
  for (int idx = t; idx < 5 * D; idx += 256) {
    int w = idx / D, dd = idx % D;
    float p = 0.f;
    #pragma unroll
    for (int s2 = 0; s2 < SL; ++s2) p += part[(s2 * 5 + w) * D + dd];
    p /= (cnt[w] + EPSF);
    proto[w * D + dd] = p;
    atomicAdd(&nrm[w], p * p);
  }
  __syncthreads();
  if (t < 25) {
    int w = t / 5, v = t % 5;
    float sdot = 0.f;
    for (int dd = 0; dd < D; ++dd) sdot += proto[w * D + dd] * proto[v * D + dd];
    dots[t] = sdot / ((sqrtf(nrm[w]) + EPSF) * (sqrtf(nrm[v]) + EPSF));
  }
  __syncthreads();
  if (t < 25) {
    int w = t / 5;
    float m = dots[w * 5];
    #pragma unroll
    for (int u = 1; u < 5; ++u) m = fmaxf(m, dots[w * 5 + u]);
    float ssum = 0.f;
    #pragma unroll
    for (int u = 0; u < 5; ++u) ssum += expf(dots[w * 5 + u] - m);
    dst[(size_t)b * 64 + parkoff + t] = expf(dots[t] - m) / ssum;
  }
}

// ---------------- 3. transpose rows 256..511 of A: At[b][j][i] = A[b][256+i][j] ----------------
__global__ __launch_bounds__(256) void k_At(const float* __restrict__ A, float* __restrict__ Atr) {
  __shared__ float T[64][65];
  int bid = blockIdx.x;
  int b = bid >> 5, r = bid & 31, jt = r >> 2, it = r & 3;
  int j0 = jt * 64, i0 = it * 64;
  int t = threadIdx.x;
  #pragma unroll
  for (int c = 0; c < 4; ++c) {
    int flat = (t + c * 256) * 4;
    int ii = flat >> 6, jj = flat & 63;
    float4 v = *(const float4*)(A + ((size_t)b * 512 + 256 + i0 + ii) * 512 + j0 + jj);
    T[ii][jj] = v.x; T[ii][jj + 1] = v.y; T[ii][jj + 2] = v.z; T[ii][jj + 3] = v.w;
  }
  __syncthreads();
  #pragma unroll
  for (int c = 0; c < 4; ++c) {
    int flat = (t + c * 256) * 4;
    int jj = flat >> 6, ii = flat & 63;
    float4 v = make_float4(T[ii][jj], T[ii + 1][jj], T[ii + 2][jj], T[ii + 3][jj]);
    *(float4*)(Atr + ((size_t)b * 512 + j0 + jj) * 256 + i0 + ii) = v;
  }
}

// ---------------- 4. per-round BP: grid = 3 rounds x 128 batches, A register-resident ----------------
__global__ __launch_bounds__(1024, 4) void k_bp(const float* __restrict__ Atr,
                                                const float* __restrict__ unary,
                                                const float* __restrict__ binc,
                                                const int* __restrict__ labels,
                                                float* __restrict__ out) {
  __shared__ float cbuf[256 * 8];   // c[j][0..4], stride 8 (b128-aligned)
  __shared__ float b3s[256 * 5];    // free-node beliefs
  __shared__ float msg[256 * 5];    // atomic combine; stride 5, gcd(5,32)=1 -> conflict-free
  __shared__ float binl[5 * 8];
  __shared__ int labs[256];
  int bid = blockIdx.x;
  int r = bid % 3, b = bid / 3;
  int t = threadIdx.x;
  int w = t >> 6, l = t & 63;
  int wh = w & 1, jc = w >> 1;      // i-half, j-chunk [32*jc, 32*jc+32)
  int i0 = wh * 128 + l;            // lane's i values: i0, i0+64
  if (t < 256) labs[t] = labels[b * 512 + t];
  if (t < 25) {
    float val;
    if (r == 0)      val = binc[b * 25 + t];
    else if (r == 1) val = out[PARKB + (size_t)b * 64 + t];
    else             val = out[PARKB + (size_t)b * 64 + 32 + t];
    binl[(t / 5) * 8 + (t % 5)] = val;
  }
  __syncthreads();
  // P1 (t<256): unary load (kept in regs), b0 = softmax(u), support-c into cbuf
  float u[5] = {};
  if (t < 256) {
    size_t ub = ((size_t)b * 512 + 256 + t) * 5;
    #pragma unroll
    for (int v = 0; v < 5; ++v) u[v] = unary[ub + v];
    float m = u[0];
    #pragma unroll
    for (int v = 1; v < 5; ++v) m = fmaxf(m, u[v]);
    float e[5], ssum = 0.f;
    #pragma unroll
    for (int v = 0; v < 5; ++v) { e[v] = expf(u[v] - m); ssum += e[v]; }
    float inv = 1.f / ssum;
    #pragma unroll
    for (int v = 0; v < 5; ++v) b3s[t * 5 + v] = e[v] * inv;
    int lab = labs[t];
    #pragma unroll
    for (int v = 0; v < 5; ++v) cbuf[t * 8 + v] = binl[lab * 8 + v];
  }
  __syncthreads();
  // P2: support partial (regs) + free-block A -> regs (held across all iterations)
  float asup[2][5] = {};
  float af[32][2];
  #pragma unroll
  for (int jj = 0; jj < 32; ++jj) {
    int j = jc * 32 + jj;
    float4 cq = *(const float4*)&cbuf[j * 8];
    float c4 = cbuf[j * 8 + 4];
    float ck[5] = {cq.x, cq.y, cq.z, cq.w, c4};
    size_t sbase = ((size_t)b * 512 + j) * 256 + i0;
    float a0 = Atr[sbase], a1 = Atr[sbase + 64];
    #pragma unroll
    for (int k = 0; k < 5; ++k) { asup[0][k] += a0 * ck[k]; asup[1][k] += a1 * ck[k]; }
    size_t fbase = ((size_t)b * 512 + 256 + j) * 256 + i0;
    af[jj][0] = Atr[fbase]; af[jj][1] = Atr[fbase + 64];
  }
  __syncthreads();
  for (int it = 0; it < BP_ITERS; ++it) {
    // A-phase (t<256): c[t] = b[t] @ binary ; zero ALL 1280 msg entries
    if (t < 256) {
      float bb[5];
      #pragma unroll
      for (int v = 0; v < 5; ++v) bb[v] = b3s[t * 5 + v];
      #pragma unroll
      for (int v = 0; v < 5; ++v) {
        float s = 0.f;
        #pragma unroll
        for (int ww = 0; ww < 5; ++ww) s += bb[ww] * binl[ww * 8 + v];
        cbuf[t * 8 + v] = s;
      }
    }
    msg[t] = 0.f;                         // t<1024 -> msg[0..1023]
    if (t < 256) msg[t + 1024] = 0.f;     // msg[1024..1279]
    __syncthreads();
    // B-phase: 16 waves, register A
    {
      float acc[2][5];
      #pragma unroll
      for (int g = 0; g < 2; ++g)
        #pragma unroll
        for (int k = 0; k < 5; ++k) acc[g][k] = asup[g][k];
      #pragma unroll
      for (int jj = 0; jj < 32; ++jj) {
        int j = jc * 32 + jj;
        float4 cq = *(const float4*)&cbuf[j * 8];
        float c4 = cbuf[j * 8 + 4];
        float ck[5] = {cq.x, cq.y, cq.z, cq.w, c4};
        #pragma unroll
        for (int k = 0; k < 5; ++k) {
          acc[0][k] += af[jj][0] * ck[k];
          acc[1][k] += af[jj][1] * ck[k];
        }
      }
      #pragma unroll
      for (int g = 0; g < 2; ++g)
        #pragma unroll
        for (int k = 0; k < 5; ++k) atomicAdd(&msg[(i0 + 64 * g) * 5 + k], acc[g][k]);
    }
    __syncthreads();
    // C-phase (t<256): b = softmax(u + msg)
    if (t < 256) {
      float lg[5];
      #pragma unroll
      for (int v = 0; v < 5; ++v) lg[v] = u[v] + msg[t * 5 + v];
      float m = lg[0];
      #pragma unroll
      for (int v = 1; v < 5; ++v) m = fmaxf(m, lg[v]);
      float e[5], ssum = 0.f;
      #pragma unroll
      for (int v = 0; v < 5; ++v) { e[v] = expf(lg[v] - m); ssum += e[v]; }
      float inv = 1.f / ssum;
      #pragma unroll
      for (int v = 0; v < 5; ++v) b3s[t * 5 + v] = e[v] * inv;
    }
    __syncthreads();
  }
  // P4 (t<512): write this round's clamped beliefs
  if (t < 512) {
    int n = t;
    float bel[5];
    if (n < 256) {
      int lab = labs[n];
      #pragma unroll
      for (int v = 0; v < 5; ++v) bel[v] = (v == lab) ? 1.f : 0.f;
    } else {
      #pragma unroll
      for (int v = 0; v < 5; ++v) bel[v] = b3s[(n - 256) * 5 + v];
    }
    size_t base = OFF_B1 + (size_t)r * 327680ull + ((size_t)b * 512 + n) * 5;
    #pragma unroll
    for (int v = 0; v < 5; ++v) out[base + v] = bel[v];
  }
}

// ---------------- 5. fused affinity pass (vectorized): A-copy + aff1 + aff2 + aff3 ----------------
__global__ __launch_bounds__(256) void k_aff(const float* __restrict__ A, float* __restrict__ out) {
  __shared__ float belT[16][520];   // [k][j]: k=r*5+v (15 used), padded
  int bid = blockIdx.x;
  int b = bid >> 5, tile = bid & 31;
  int r0 = tile * 16;
  int t = threadIdx.x, w = t >> 6, l = t & 63;
  for (int idx = t; idx < 2560; idx += 256) {
    int j = idx / 5, v = idx % 5;
    belT[v][j]      = out[OFF_B1 + (size_t)b * 2560 + idx];
    belT[5 + v][j]  = out[OFF_B2 + (size_t)b * 2560 + idx];
    belT[10 + v][j] = out[OFF_B3 + (size_t)b * 2560 + idx];
  }
  __syncthreads();
  #pragma unroll 1
  for (int rr = 0; rr < 4; ++rr) {
    int row = r0 + w * 4 + rr;
    size_t base = ((size_t)b * 512 + row) * 512;
    float bi[15];
    #pragma unroll
    for (int k = 0; k < 15; ++k) bi[k] = belT[k][row];
    float4 a[2];
    float s1[2][4], s2[2][4], s3[2][4];
    float p1 = 0.f, p2 = 0.f, p3 = 0.f;
    #pragma unroll
    for (int g = 0; g < 2; ++g) {
      int c0 = g * 256 + l * 4;
      a[g] = *(const float4*)(A + base + c0);
      float4 bv[15];
      #pragma unroll
      for (int k = 0; k < 15; ++k) bv[k] = *(const float4*)&belT[k][c0];
      #pragma unroll
      for (int e = 0; e < 4; ++e) {
        float ae = ((const float*)&a[g])[e];
        float t1 = 0.f, t2 = 0.f, t3 = 0.f;
        #pragma unroll
        for (int v = 0; v < 5; ++v) {
          t1 += bi[v]      * ((const float*)&bv[v])[e];
          t2 += bi[5 + v]  * ((const float*)&bv[5 + v])[e];
          t3 += bi[10 + v] * ((const float*)&bv[10 + v])[e];
        }
        s1[g][e] = t1; s2[g][e] = t2; s3[g][e] = t3;
        p1 += ae * t1; p2 += ae * t2; p3 += ae * t3;
      }
    }
    #pragma unroll
    for (int off = 1; off < 64; off <<= 1) {
      p1 += __shfl_xor(p1, off, 64);
      p2 += __shfl_xor(p2, off, 64);
      p3 += __shfl_xor(p3, off, 64);
    }
    float inv1 = 1.f / (p1 + EPSF), inv2 = 1.f / (p2 + EPSF), inv3 = 1.f / (p3 + EPSF);
    #pragma unroll
    for (int g = 0; g < 2; ++g) {
      int c0 = g * 256 + l * 4;
      float4 o1, o2, o3;
      #pragma unroll
      for (int e = 0; e < 4; ++e) {
        float ae = ((const float*)&a[g])[e];
        ((float*)&o1)[e] = ae * s1[g][e] * inv1;
        ((float*)&o2)[e] = ae * s2[g][e] * inv2;
        ((float*)&o3)[e] = ae * s3[g][e] * inv3;
      }
      *(float4*)(out + OFF_A   + base + c0) = a[g];
      *(float4*)(out + OFF_AF1 + base + c0) = o1;
      *(float4*)(out + OFF_AF2 + base + c0) = o2;
      *(float4*)(out + OFF_AF3 + base + c0) = o3;
    }
  }
}

extern "C" void kernel_launch(void* const* d_in, const int* in_sizes, int n_in,
                              void* d_out, int out_size, void* d_ws, size_t ws_size,
                              hipStream_t stream) {
  (void)in_sizes; (void)n_in; (void)out_size; (void)d_ws; (void)ws_size;
  const float* inp  = (const float*)d_in[0];
  const float* aff  = (const float*)d_in[1];
  const float* una  = (const float*)d_in[2];
  const float* binc = (const float*)d_in[3];
  const int*   lab  = (const int*)d_in[4];
  const float* W1 = (const float*)d_in[6];
  const float* b1 = (const float*)d_in[7];
  const float* W2 = (const float*)d_in[8];
  const float* b2 = (const float*)d_in[9];
  float* out = (float*)d_out;

  k_mgemm<64, false><<<512, 256, 0, stream>>>(inp, 65536, W1, 0, out + Y1_OFF, nullptr, 128);
  k_mgemm<64, true ><<<512, 256, 0, stream>>>(aff, 262144, out + Y1_OFF, 32768, out + X1_OFF, b1, 512);
  k_bc<64><<<128, 256, 0, stream>>>(out + X1_OFF, lab, out + PARKB, 0);
  k_mgemm<32, false><<<512, 256, 0, stream>>>(out + X1_OFF, 32768, W2, 0, out + Y2_OFF, nullptr, 64);
  k_mgemm<32, true ><<<512, 256, 0, stream>>>(aff, 262144, out + Y2_OFF, 16384, out + X2_OFF, b2, 512);
  k_bc<32><<<128, 256, 0, stream>>>(out + X2_OFF, lab, out + PARKB, 32);
  k_At<<<4096, 256, 0, stream>>>(aff, out + AT_OFF);
  k_bp<<<384, 1024, 0, stream>>>(out + AT_OFF, una, binc, lab, out);
  k_aff<<<4096, 256, 0, stream>>>(aff, out);
}

// Round 7
// 619.046 us; speedup vs baseline: 1.0604x; 1.0604x over previous
//
#include <hip/hip_runtime.h>
#include <math.h>

#define EPSF 1e-6f
#define BP_ITERS 7

// ---- d_out layout (float offsets) ----
#define OFF_A    0ull
#define OFF_B1   33554432ull
#define OFF_B2   33882112ull
#define OFF_B3   34209792ull
#define OFF_AF1  34537472ull
#define OFF_AF2  68091904ull
#define OFF_AF3  101646336ull
// scratch parked inside d_out (regions dead until later kernels overwrite them)
#define Y1_OFF  (OFF_AF1)                 // [B][512][64] fp32
#define X1_OFF  (OFF_AF1 + 4194304ull)    // [B][512][64] fp32
#define Y2_OFF  (OFF_AF2)                 // [B][512][32] fp32
#define X2_OFF  (OFF_AF2 + 2097152ull)    // [B][512][32] fp32
#define AT_OFF  (OFF_AF2 + 4194304ull)    // At[b][j(512)][i(256)] = A[b][256+i][j], 16777216 floats
#define PARKB   (OFF_AF2 + 20971520ull)   // bc1/bc2 park: b*64 + {0,32}; overwritten only by k_aff

typedef __attribute__((ext_vector_type(8))) short bf16x8;
typedef __attribute__((ext_vector_type(4))) short s16x4;
typedef __attribute__((ext_vector_type(4))) float f32x4;

__device__ __forceinline__ short f2bf(float f) {
  unsigned u = __float_as_uint(f);
  unsigned r = (u + 0x7fffu + ((u >> 16) & 1u)) >> 16;
  return (short)r;
}
__device__ __forceinline__ float bf2f(short h) {
  return __uint_as_float(((unsigned)(unsigned short)h) << 16);
}

// ---------------- 1. split-bf16 MFMA GEMM: C[b](512xBN) = A[b](512xK) @ B(KxBN) ----------------
// POST: fused rowsum(A-tile-rows) during staging (16-lane shfl reduce -> 1 atomic per group);
//       epilogue relu(acc/(rs+eps)+bias)
template<int BN, bool POST>
__global__ __launch_bounds__(256) void k_mgemm(const float* __restrict__ Ain, size_t astride,
                                               const float* __restrict__ Bin, size_t bstride,
                                               float* __restrict__ Cout,
                                               const float* __restrict__ bias, int K) {
  constexpr int BM = 128, BK = 64, LDA = BK + 8;
  constexpr int NF = BN / 16;
  __shared__ short Ahi[BM * LDA], Alo[BM * LDA];
  __shared__ short Bhi[BN * LDA], Blo[BN * LDA];
  __shared__ float rs[BM];
  __shared__ float bls[BN];
  int b = blockIdx.x >> 2, mt = blockIdx.x & 3;
  int m0 = mt * BM;
  int t = threadIdx.x;
  int w = t >> 6, l = t & 63;
  if constexpr (POST) {
    if (t < BM) rs[t] = 0.f;
    if (t < BN) bls[t] = bias[t];
    __syncthreads();
  }
  const float* Ab = Ain + (size_t)b * astride + (size_t)m0 * K;
  const float* Bb = Bin + (size_t)b * bstride;
  f32x4 acc[2][NF];
  #pragma unroll
  for (int mf = 0; mf < 2; ++mf)
    #pragma unroll
    for (int nf = 0; nf < NF; ++nf) acc[mf][nf] = (f32x4){0.f, 0.f, 0.f, 0.f};

  for (int kt = 0; kt < K; kt += BK) {
    #pragma unroll
    for (int i = 0; i < 8; ++i) {
      int f = (t + i * 256) * 4;
      int r = f >> 6, k = f & 63;
      float4 v = *(const float4*)(Ab + (size_t)r * K + kt + k);
      if constexpr (POST) {
        // 16 consecutive lanes share row r (aligned group) -> shfl tree + 1 atomic/group
        float s4 = v.x + v.y + v.z + v.w;
        #pragma unroll
        for (int off = 1; off < 16; off <<= 1) s4 += __shfl_xor(s4, off, 64);
        if ((l & 15) == 0) atomicAdd(&rs[r], s4);
      }
      float xs[4] = {v.x, v.y, v.z, v.w};
      s16x4 h, lo;
      #pragma unroll
      for (int e = 0; e < 4; ++e) {
        h[e] = f2bf(xs[e]);
        lo[e] = f2bf(xs[e] - bf2f(h[e]));
      }
      *(s16x4*)&Ahi[r * LDA + k] = h;
      *(s16x4*)&Alo[r * LDA + k] = lo;
    }
    #pragma unroll
    for (int i = 0; i < BK * BN / 1024; ++i) {
      int f = (t + i * 256) * 4;
      int k = f / BN, n = f % BN;
      float4 v = *(const float4*)(Bb + (size_t)(kt + k) * BN + n);
      float xs[4] = {v.x, v.y, v.z, v.w};
      #pragma unroll
      for (int e = 0; e < 4; ++e) {
        short h = f2bf(xs[e]);
        Bhi[(n + e) * LDA + k] = h;
        Blo[(n + e) * LDA + k] = f2bf(xs[e] - bf2f(h));
      }
    }
    __syncthreads();
    #pragma unroll
    for (int kc = 0; kc < 2; ++kc) {
      int kb = kc * 32 + (l >> 4) * 8;
      bf16x8 ah[2], al[2];
      #pragma unroll
      for (int mf = 0; mf < 2; ++mf) {
        int row = w * 32 + mf * 16 + (l & 15);
        ah[mf] = *(const bf16x8*)&Ahi[row * LDA + kb];
        al[mf] = *(const bf16x8*)&Alo[row * LDA + kb];
      }
      #pragma unroll
      for (int nf = 0; nf < NF; ++nf) {
        int col = nf * 16 + (l & 15);
        bf16x8 bh = *(const bf16x8*)&Bhi[col * LDA + kb];
        bf16x8 bl = *(const bf16x8*)&Blo[col * LDA + kb];
        #pragma unroll
        for (int mf = 0; mf < 2; ++mf) {
          acc[mf][nf] = __builtin_amdgcn_mfma_f32_16x16x32_bf16(ah[mf], bh, acc[mf][nf], 0, 0, 0);
          acc[mf][nf] = __builtin_amdgcn_mfma_f32_16x16x32_bf16(ah[mf], bl, acc[mf][nf], 0, 0, 0);
          acc[mf][nf] = __builtin_amdgcn_mfma_f32_16x16x32_bf16(al[mf], bh, acc[mf][nf], 0, 0, 0);
        }
      }
    }
    __syncthreads();
  }
  #pragma unroll
  for (int mf = 0; mf < 2; ++mf) {
    #pragma unroll
    for (int nf = 0; nf < NF; ++nf) {
      int col = nf * 16 + (l & 15);
      #pragma unroll
      for (int i = 0; i < 4; ++i) {
        int rloc = w * 32 + mf * 16 + (l >> 4) * 4 + i;
        float x = acc[mf][nf][i];
        if constexpr (POST) x = fmaxf(x / (rs[rloc] + EPSF) + bls[col], 0.f);
        Cout[((size_t)b * 512 + m0 + rloc) * BN + col] = x;
      }
    }
  }
}

// ---------------- 2. binary_comp_calc ----------------
template<int D>
__global__ __launch_bounds__(256) void k_bc(const float* __restrict__ X, const int* __restrict__ labels,
                                            float* __restrict__ dst, int parkoff) {
  constexpr int SL = 256 / D;
  constexpr int NPER = 512 / SL;
  __shared__ int labs[512];
  __shared__ float part[SL * 5 * D];
  __shared__ float cnt[5], nrm[5], proto[5 * D], dots[25];
  int b = blockIdx.x, t = threadIdx.x;
  labs[t] = labels[b * 512 + t];
  labs[t + 256] = labels[b * 512 + 256 + t];
  if (t < 5) { cnt[t] = 0.f; nrm[t] = 0.f; }
  __syncthreads();
  if (t < 128) {
    #pragma unroll
    for (int k = 0; k < 4; ++k) atomicAdd(&cnt[labs[t * 4 + k]], 1.f);
  }
  {
    int s = t / D, d = t % D;
    float a5[5] = {};
    for (int k = 0; k < NPER; ++k) {
      int n = s * NPER + k;
      float x = X[((size_t)b * 512 + n) * D + d];
      int lab = labs[n];
      #pragma unroll
      for (int w = 0; w < 5; ++w) a5[w] += (lab == w) ? x : 0.f;
    }
    #pragma unroll
    for (int w = 0; w < 5; ++w) part[(s * 5 + w) * D + d] = a5[w];
  }
  __syncthreads();
  for (int idx = t; idx < 5 * D; idx += 256) {
    int w = idx / D, dd = idx % D;
    float p = 0.f;
    #pragma unroll
    for (int s2 = 0; s2 < SL; ++s2) p += part[(s2 * 5 + w) * D + dd];
    p /= (cnt[w] + EPSF);
    proto[w * D + dd] = p;
    atomicAdd(&nrm[w], p * p);
  }
  __syncthreads();
  if (t < 25) {
    int w = t / 5, v = t % 5;
    float sdot = 0.f;
    for (int dd = 0; dd < D; ++dd) sdot += proto[w * D + dd] * proto[v * D + dd];
    dots[t] = sdot / ((sqrtf(nrm[w]) + EPSF) * (sqrtf(nrm[v]) + EPSF));
  }
  __syncthreads();
  if (t < 25) {
    int w = t / 5;
    float m = dots[w * 5];
    #pragma unroll
    for (int u = 1; u < 5; ++u) m = fmaxf(m, dots[w * 5 + u]);
    float ssum = 0.f;
    #pragma unroll
    for (int u = 0; u < 5; ++u) ssum += expf(dots[w * 5 + u] - m);
    dst[(size_t)b * 64 + parkoff + t] = expf(dots[t] - m) / ssum;
  }
}

// ---------------- 3. transpose rows 256..511 of A: At[b][j][i] = A[b][256+i][j] ----------------
__global__ __launch_bounds__(256) void k_At(const float* __restrict__ A, float* __restrict__ Atr) {
  __shared__ float T[64][65];
  int bid = blockIdx.x;
  int b = bid >> 5, r = bid & 31, jt = r >> 2, it = r & 3;
  int j0 = jt * 64, i0 = it * 64;
  int t = threadIdx.x;
  #pragma unroll
  for (int c = 0; c < 4; ++c) {
    int flat = (t + c * 256) * 4;
    int ii = flat >> 6, jj = flat & 63;
    float4 v = *(const float4*)(A + ((size_t)b * 512 + 256 + i0 + ii) * 512 + j0 + jj);
    T[ii][jj] = v.x; T[ii][jj + 1] = v.y; T[ii][jj + 2] = v.z; T[ii][jj + 3] = v.w;
  }
  __syncthreads();
  #pragma unroll
  for (int c = 0; c < 4; ++c) {
    int flat = (t + c * 256) * 4;
    int jj = flat >> 6, ii = flat & 63;
    float4 v = make_float4(T[ii][jj], T[ii + 1][jj], T[ii + 2][jj], T[ii + 3][jj]);
    *(float4*)(Atr + ((size_t)b * 512 + j0 + jj) * 256 + i0 + ii) = v;
  }
}

// ---------------- 4. per-round BP: grid = 3 rounds x 128 batches, A register-resident ----------------
__global__ __launch_bounds__(1024, 4) void k_bp(const float* __restrict__ Atr,
                                                const float* __restrict__ unary,
                                                const float* __restrict__ binc,
                                                const int* __restrict__ labels,
                                                float* __restrict__ out) {
  __shared__ float cbuf[256 * 8];   // c[j][0..4], stride 8 (b128-aligned)
  __shared__ float b3s[256 * 5];    // free-node beliefs
  __shared__ float msg[256 * 5];    // atomic combine; stride 5, gcd(5,32)=1 -> conflict-free
  __shared__ float binl[5 * 8];
  __shared__ int labs[256];
  int bid = blockIdx.x;
  int r = bid % 3, b = bid / 3;
  int t = threadIdx.x;
  int w = t >> 6, l = t & 63;
  int wh = w & 1, jc = w >> 1;      // i-half, j-chunk [32*jc, 32*jc+32)
  int i0 = wh * 128 + l;            // lane's i values: i0, i0+64
  if (t < 256) labs[t] = labels[b * 512 + t];
  if (t < 25) {
    float val;
    if (r == 0)      val = binc[b * 25 + t];
    else if (r == 1) val = out[PARKB + (size_t)b * 64 + t];
    else             val = out[PARKB + (size_t)b * 64 + 32 + t];
    binl[(t / 5) * 8 + (t % 5)] = val;
  }
  __syncthreads();
  // P1 (t<256): unary load (kept in regs), b0 = softmax(u), support-c into cbuf
  float u[5] = {};
  if (t < 256) {
    size_t ub = ((size_t)b * 512 + 256 + t) * 5;
    #pragma unroll
    for (int v = 0; v < 5; ++v) u[v] = unary[ub + v];
    float m = u[0];
    #pragma unroll
    for (int v = 1; v < 5; ++v) m = fmaxf(m, u[v]);
    float e[5], ssum = 0.f;
    #pragma unroll
    for (int v = 0; v < 5; ++v) { e[v] = expf(u[v] - m); ssum += e[v]; }
    float inv = 1.f / ssum;
    #pragma unroll
    for (int v = 0; v < 5; ++v) b3s[t * 5 + v] = e[v] * inv;
    int lab = labs[t];
    #pragma unroll
    for (int v = 0; v < 5; ++v) cbuf[t * 8 + v] = binl[lab * 8 + v];
  }
  __syncthreads();
  // P2: support partial (regs) + free-block A -> regs (held across all iterations)
  float asup[2][5] = {};
  float af[32][2];
  #pragma unroll
  for (int jj = 0; jj < 32; ++jj) {
    int j = jc * 32 + jj;
    float4 cq = *(const float4*)&cbuf[j * 8];
    float c4 = cbuf[j * 8 + 4];
    float ck[5] = {cq.x, cq.y, cq.z, cq.w, c4};
    size_t sbase = ((size_t)b * 512 + j) * 256 + i0;
    float a0 = Atr[sbase], a1 = Atr[sbase + 64];
    #pragma unroll
    for (int k = 0; k < 5; ++k) { asup[0][k] += a0 * ck[k]; asup[1][k] += a1 * ck[k]; }
    size_t fbase = ((size_t)b * 512 + 256 + j) * 256 + i0;
    af[jj][0] = Atr[fbase]; af[jj][1] = Atr[fbase + 64];
  }
  __syncthreads();
  for (int it = 0; it < BP_ITERS; ++it) {
    // A-phase (t<256): c[t] = b[t] @ binary ; zero ALL 1280 msg entries
    if (t < 256) {
      float bb[5];
      #pragma unroll
      for (int v = 0; v < 5; ++v) bb[v] = b3s[t * 5 + v];
      #pragma unroll
      for (int v = 0; v < 5; ++v) {
        float s = 0.f;
        #pragma unroll
        for (int ww = 0; ww < 5; ++ww) s += bb[ww] * binl[ww * 8 + v];
        cbuf[t * 8 + v] = s;
      }
    }
    msg[t] = 0.f;                         // t<1024 -> msg[0..1023]
    if (t < 256) msg[t + 1024] = 0.f;     // msg[1024..1279]
    __syncthreads();
    // B-phase: 16 waves, register A
    {
      float acc[2][5];
      #pragma unroll
      for (int g = 0; g < 2; ++g)
        #pragma unroll
        for (int k = 0; k < 5; ++k) acc[g][k] = asup[g][k];
      #pragma unroll
      for (int jj = 0; jj < 32; ++jj) {
        int j = jc * 32 + jj;
        float4 cq = *(const float4*)&cbuf[j * 8];
        float c4 = cbuf[j * 8 + 4];
        float ck[5] = {cq.x, cq.y, cq.z, cq.w, c4};
        #pragma unroll
        for (int k = 0; k < 5; ++k) {
          acc[0][k] += af[jj][0] * ck[k];
          acc[1][k] += af[jj][1] * ck[k];
        }
      }
      #pragma unroll
      for (int g = 0; g < 2; ++g)
        #pragma unroll
        for (int k = 0; k < 5; ++k) atomicAdd(&msg[(i0 + 64 * g) * 5 + k], acc[g][k]);
    }
    __syncthreads();
    // C-phase (t<256): b = softmax(u + msg)
    if (t < 256) {
      float lg[5];
      #pragma unroll
      for (int v = 0; v < 5; ++v) lg[v] = u[v] + msg[t * 5 + v];
      float m = lg[0];
      #pragma unroll
      for (int v = 1; v < 5; ++v) m = fmaxf(m, lg[v]);
      float e[5], ssum = 0.f;
      #pragma unroll
      for (int v = 0; v < 5; ++v) { e[v] = expf(lg[v] - m); ssum += e[v]; }
      float inv = 1.f / ssum;
      #pragma unroll
      for (int v = 0; v < 5; ++v) b3s[t * 5 + v] = e[v] * inv;
    }
    __syncthreads();
  }
  // P4 (t<512): write this round's clamped beliefs
  if (t < 512) {
    int n = t;
    float bel[5];
    if (n < 256) {
      int lab = labs[n];
      #pragma unroll
      for (int v = 0; v < 5; ++v) bel[v] = (v == lab) ? 1.f : 0.f;
    } else {
      #pragma unroll
      for (int v = 0; v < 5; ++v) bel[v] = b3s[(n - 256) * 5 + v];
    }
    size_t base = OFF_B1 + (size_t)r * 327680ull + ((size_t)b * 512 + n) * 5;
    #pragma unroll
    for (int v = 0; v < 5; ++v) out[base + v] = bel[v];
  }
}

// ---------------- 5. fused affinity pass (vectorized): A-copy + aff1 + aff2 + aff3 ----------------
__global__ __launch_bounds__(256) void k_aff(const float* __restrict__ A, float* __restrict__ out) {
  __shared__ float belT[16][520];   // [k][j]: k=r*5+v (15 used), padded
  int bid = blockIdx.x;
  int b = bid >> 5, tile = bid & 31;
  int r0 = tile * 16;
  int t = threadIdx.x, w = t >> 6, l = t & 63;
  for (int idx = t; idx < 2560; idx += 256) {
    int j = idx / 5, v = idx % 5;
    belT[v][j]      = out[OFF_B1 + (size_t)b * 2560 + idx];
    belT[5 + v][j]  = out[OFF_B2 + (size_t)b * 2560 + idx];
    belT[10 + v][j] = out[OFF_B3 + (size_t)b * 2560 + idx];
  }
  __syncthreads();
  #pragma unroll 1
  for (int rr = 0; rr < 4; ++rr) {
    int row = r0 + w * 4 + rr;
    size_t base = ((size_t)b * 512 + row) * 512;
    float bi[15];
    #pragma unroll
    for (int k = 0; k < 15; ++k) bi[k] = belT[k][row];
    float4 a[2];
    float s1[2][4], s2[2][4], s3[2][4];
    float p1 = 0.f, p2 = 0.f, p3 = 0.f;
    #pragma unroll
    for (int g = 0; g < 2; ++g) {
      int c0 = g * 256 + l * 4;
      a[g] = *(const float4*)(A + base + c0);
      float4 bv[15];
      #pragma unroll
      for (int k = 0; k < 15; ++k) bv[k] = *(const float4*)&belT[k][c0];
      #pragma unroll
      for (int e = 0; e < 4; ++e) {
        float ae = ((const float*)&a[g])[e];
        float t1 = 0.f, t2 = 0.f, t3 = 0.f;
        #pragma unroll
        for (int v = 0; v < 5; ++v) {
          t1 += bi[v]      * ((const float*)&bv[v])[e];
          t2 += bi[5 + v]  * ((const float*)&bv[5 + v])[e];
          t3 += bi[10 + v] * ((const float*)&bv[10 + v])[e];
        }
        s1[g][e] = t1; s2[g][e] = t2; s3[g][e] = t3;
        p1 += ae * t1; p2 += ae * t2; p3 += ae * t3;
      }
    }
    #pragma unroll
    for (int off = 1; off < 64; off <<= 1) {
      p1 += __shfl_xor(p1, off, 64);
      p2 += __shfl_xor(p2, off, 64);
      p3 += __shfl_xor(p3, off, 64);
    }
    float inv1 = 1.f / (p1 + EPSF), inv2 = 1.f / (p2 + EPSF), inv3 = 1.f / (p3 + EPSF);
    #pragma unroll
    for (int g = 0; g < 2; ++g) {
      int c0 = g * 256 + l * 4;
      float4 o1, o2, o3;
      #pragma unroll
      for (int e = 0; e < 4; ++e) {
        float ae = ((const float*)&a[g])[e];
        ((float*)&o1)[e] = ae * s1[g][e] * inv1;
        ((float*)&o2)[e] = ae * s2[g][e] * inv2;
        ((float*)&o3)[e] = ae * s3[g][e] * inv3;
      }
      *(float4*)(out + OFF_A   + base + c0) = a[g];
      *(float4*)(out + OFF_AF1 + base + c0) = o1;
      *(float4*)(out + OFF_AF2 + base + c0) = o2;
      *(float4*)(out + OFF_AF3 + base + c0) = o3;
    }
  }
}

extern "C" void kernel_launch(void* const* d_in, const int* in_sizes, int n_in,
                              void* d_out, int out_size, void* d_ws, size_t ws_size,
                              hipStream_t stream) {
  (void)in_sizes; (void)n_in; (void)out_size; (void)d_ws; (void)ws_size;
  const float* inp  = (const float*)d_in[0];
  const float* aff  = (const float*)d_in[1];
  const float* una  = (const float*)d_in[2];
  const float* binc = (const float*)d_in[3];
  const int*   lab  = (const int*)d_in[4];
  const float* W1 = (const float*)d_in[6];
  const float* b1 = (const float*)d_in[7];
  const float* W2 = (const float*)d_in[8];
  const float* b2 = (const float*)d_in[9];
  float* out = (float*)d_out;

  k_mgemm<64, false><<<512, 256, 0, stream>>>(inp, 65536, W1, 0, out + Y1_OFF, nullptr, 128);
  k_mgemm<64, true ><<<512, 256, 0, stream>>>(aff, 262144, out + Y1_OFF, 32768, out + X1_OFF, b1, 512);
  k_bc<64><<<128, 256, 0, stream>>>(out + X1_OFF, lab, out + PARKB, 0);
  k_mgemm<32, false><<<512, 256, 0, stream>>>(out + X1_OFF, 32768, W2, 0, out + Y2_OFF, nullptr, 64);
  k_mgemm<32, true ><<<512, 256, 0, stream>>>(aff, 262144, out + Y2_OFF, 16384, out + X2_OFF, b2, 512);
  k_bc<32><<<128, 256, 0, stream>>>(out + X2_OFF, lab, out + PARKB, 32);
  k_At<<<4096, 256, 0, stream>>>(aff, out + AT_OFF);
  k_bp<<<384, 1024, 0, stream>>>(out + AT_OFF, una, binc, lab, out);
  k_aff<<<4096, 256, 0, stream>>>(aff, out);
}

// Round 9
// 513.601 us; speedup vs baseline: 1.2781x; 1.2053x over previous
//
#include <hip/hip_runtime.h>
#include <math.h>

#define EPSF 1e-6f
#define BP_ITERS 7

// ---- d_out layout (float offsets) ----
#define OFF_A    0ull
#define OFF_B1   33554432ull
#define OFF_B2   33882112ull
#define OFF_B3   34209792ull
#define OFF_AF1  34537472ull
#define OFF_AF2  68091904ull
#define OFF_AF3  101646336ull
// scratch parked inside d_out (regions dead until later kernels overwrite them)
#define Y1_OFF  (OFF_AF1)                 // [B][512][64] fp32
#define X1_OFF  (OFF_AF1 + 4194304ull)    // [B][512][64] fp32
#define Y2_OFF  (OFF_AF2)                 // [B][512][32] fp32
#define X2_OFF  (OFF_AF2 + 2097152ull)    // [B][512][32] fp32
#define AT_OFF  (OFF_AF2 + 4194304ull)    // At[b][j(512)][i(256)] = A[b][256+i][j], 16777216 floats
#define PARKB   (OFF_AF2 + 20971520ull)   // bc1/bc2 park: b*64 + {0,32}; overwritten only by k_aff

typedef __attribute__((ext_vector_type(8))) short bf16x8;
typedef __attribute__((ext_vector_type(4))) short s16x4;
typedef __attribute__((ext_vector_type(4))) float f32x4;

__device__ __forceinline__ short f2bf(float f) {
  unsigned u = __float_as_uint(f);
  unsigned r = (u + 0x7fffu + ((u >> 16) & 1u)) >> 16;
  return (short)r;
}
__device__ __forceinline__ float bf2f(short h) {
  return __uint_as_float(((unsigned)(unsigned short)h) << 16);
}

// ---------------- 1. split-bf16 MFMA GEMM: C[b](512xBN) = A[b](512xK) @ B(KxBN) ----------------
// POST: rowsum(A) computed via MFMA with B=ones (free; same C/D row mapping as epilogue);
//       epilogue relu(acc/(rs+eps)+bias)
template<int BN, bool POST>
__global__ __launch_bounds__(256) void k_mgemm(const float* __restrict__ Ain, size_t astride,
                                               const float* __restrict__ Bin, size_t bstride,
                                               float* __restrict__ Cout,
                                               const float* __restrict__ bias, int K) {
  constexpr int BM = 128, BK = 64, LDA = BK + 8;
  constexpr int NF = BN / 16;
  __shared__ short Ahi[BM * LDA], Alo[BM * LDA];
  __shared__ short Bhi[BN * LDA], Blo[BN * LDA];
  __shared__ float bls[BN];
  int b = blockIdx.x >> 2, mt = blockIdx.x & 3;
  int m0 = mt * BM;
  int t = threadIdx.x;
  int w = t >> 6, l = t & 63;
  if constexpr (POST) {
    if (t < BN) bls[t] = bias[t];
  }
  const float* Ab = Ain + (size_t)b * astride + (size_t)m0 * K;
  const float* Bb = Bin + (size_t)b * bstride;
  f32x4 acc[2][NF];
  f32x4 acc_rs[2];
  bf16x8 ones;
  #pragma unroll
  for (int e = 0; e < 8; ++e) ones[e] = (short)0x3F80;
  #pragma unroll
  for (int mf = 0; mf < 2; ++mf) {
    acc_rs[mf] = (f32x4){0.f, 0.f, 0.f, 0.f};
    #pragma unroll
    for (int nf = 0; nf < NF; ++nf) acc[mf][nf] = (f32x4){0.f, 0.f, 0.f, 0.f};
  }

  for (int kt = 0; kt < K; kt += BK) {
    #pragma unroll
    for (int i = 0; i < 8; ++i) {
      int f = (t + i * 256) * 4;
      int r = f >> 6, k = f & 63;
      float4 v = *(const float4*)(Ab + (size_t)r * K + kt + k);
      float xs[4] = {v.x, v.y, v.z, v.w};
      s16x4 h, lo;
      #pragma unroll
      for (int e = 0; e < 4; ++e) {
        h[e] = f2bf(xs[e]);
        lo[e] = f2bf(xs[e] - bf2f(h[e]));
      }
      *(s16x4*)&Ahi[r * LDA + k] = h;
      *(s16x4*)&Alo[r * LDA + k] = lo;
    }
    #pragma unroll
    for (int i = 0; i < BK * BN / 1024; ++i) {
      int f = (t + i * 256) * 4;
      int k = f / BN, n = f % BN;
      float4 v = *(const float4*)(Bb + (size_t)(kt + k) * BN + n);
      float xs[4] = {v.x, v.y, v.z, v.w};
      #pragma unroll
      for (int e = 0; e < 4; ++e) {
        short h = f2bf(xs[e]);
        Bhi[(n + e) * LDA + k] = h;
        Blo[(n + e) * LDA + k] = f2bf(xs[e] - bf2f(h));
      }
    }
    __syncthreads();
    #pragma unroll
    for (int kc = 0; kc < 2; ++kc) {
      int kb = kc * 32 + (l >> 4) * 8;
      bf16x8 ah[2], al[2];
      #pragma unroll
      for (int mf = 0; mf < 2; ++mf) {
        int row = w * 32 + mf * 16 + (l & 15);
        ah[mf] = *(const bf16x8*)&Ahi[row * LDA + kb];
        al[mf] = *(const bf16x8*)&Alo[row * LDA + kb];
        if constexpr (POST) {
          acc_rs[mf] = __builtin_amdgcn_mfma_f32_16x16x32_bf16(ah[mf], ones, acc_rs[mf], 0, 0, 0);
          acc_rs[mf] = __builtin_amdgcn_mfma_f32_16x16x32_bf16(al[mf], ones, acc_rs[mf], 0, 0, 0);
        }
      }
      #pragma unroll
      for (int nf = 0; nf < NF; ++nf) {
        int col = nf * 16 + (l & 15);
        bf16x8 bh = *(const bf16x8*)&Bhi[col * LDA + kb];
        bf16x8 bl = *(const bf16x8*)&Blo[col * LDA + kb];
        #pragma unroll
        for (int mf = 0; mf < 2; ++mf) {
          acc[mf][nf] = __builtin_amdgcn_mfma_f32_16x16x32_bf16(ah[mf], bh, acc[mf][nf], 0, 0, 0);
          acc[mf][nf] = __builtin_amdgcn_mfma_f32_16x16x32_bf16(ah[mf], bl, acc[mf][nf], 0, 0, 0);
          acc[mf][nf] = __builtin_amdgcn_mfma_f32_16x16x32_bf16(al[mf], bh, acc[mf][nf], 0, 0, 0);
        }
      }
    }
    __syncthreads();
  }
  #pragma unroll
  for (int mf = 0; mf < 2; ++mf) {
    #pragma unroll
    for (int nf = 0; nf < NF; ++nf) {
      int col = nf * 16 + (l & 15);
      #pragma unroll
      for (int i = 0; i < 4; ++i) {
        int rloc = w * 32 + mf * 16 + (l >> 4) * 4 + i;
        float x = acc[mf][nf][i];
        if constexpr (POST) x = fmaxf(x / (acc_rs[mf][i] + EPSF) + bls[col], 0.f);
        Cout[((size_t)b * 512 + m0 + rloc) * BN + col] = x;
      }
    }
  }
}

// ---------------- 2. binary_comp_calc ----------------
template<int D>
__global__ __launch_bounds__(256) void k_bc(const float* __restrict__ X, const int* __restrict__ labels,
                                            float* __restrict__ dst, int parkoff) {
  constexpr int SL = 256 / D;
  constexpr int NPER = 512 / SL;
  __shared__ int labs[512];
  __shared__ float part[SL * 5 * D];
  __shared__ float cnt[5], nrm[5], proto[5 * D], dots[25];
  int b = blockIdx.x, t = threadIdx.x;
  labs[t] = labels[b * 512 + t];
  labs[t + 256] = labels[b * 512 + 256 + t];
  if (t < 5) { cnt[t] = 0.f; nrm[t] = 0.f; }
  __syncthreads();
  if (t < 128) {
    #pragma unroll
    for (int k = 0; k < 4; ++k) atomicAdd(&cnt[labs[t * 4 + k]], 1.f);
  }
  {
    int s = t / D, d = t % D;
    float a5[5] = {};
    for (int k = 0; k < NPER; ++k) {
      int n = s * NPER + k;
      float x = X[((size_t)b * 512 + n) * D + d];
      int lab = labs[n];
      #pragma unroll
      for (int w = 0; w < 5; ++w) a5[w] += (lab == w) ? x : 0.f;
    }
    #pragma unroll
    for (int w = 0; w < 5; ++w) part[(s * 5 + w) * D + d] = a5[w];
  }
  __syncthreads();
  for (int idx = t; idx < 5 * D; idx += 256) {
    int w = idx / D, dd = idx % D;
    float p = 0.f;
    #pragma unroll
    for (int s2 = 0; s2 < SL; ++s2) p += part[(s2 * 5 + w) * D + dd];
    p /= (cnt[w] + EPSF);
    proto[w * D + dd] = p;
    atomicAdd(&nrm[w], p * p);
  }
  __syncthreads();
  if (t < 25) {
    int w = t / 5, v = t % 5;
    float sdot = 0.f;
    for (int dd = 0; dd < D; ++dd) sdot += proto[w * D + dd] * proto[v * D + dd];
    dots[t] = sdot / ((sqrtf(nrm[w]) + EPSF) * (sqrtf(nrm[v]) + EPSF));
  }
  __syncthreads();
  if (t < 25) {
    int w = t / 5;
    float m = dots[w * 5];
    #pragma unroll
    for (int u = 1; u < 5; ++u) m = fmaxf(m, dots[w * 5 + u]);
    float ssum = 0.f;
    #pragma unroll
    for (int u = 0; u < 5; ++u) ssum += expf(dots[w * 5 + u] - m);
    dst[(size_t)b * 64 + parkoff + t] = expf(dots[t] - m) / ssum;
  }
}

// ---------------- 3. transpose rows 256..511 of A: At[b][j][i] = A[b][256+i][j] ----------------
__global__ __launch_bounds__(256) void k_At(const float* __restrict__ A, float* __restrict__ Atr) {
  __shared__ float T[64][65];
  int bid = blockIdx.x;
  int b = bid >> 5, r = bid & 31, jt = r >> 2, it = r & 3;
  int j0 = jt * 64, i0 = it * 64;
  int t = threadIdx.x;
  #pragma unroll
  for (int c = 0; c < 4; ++c) {
    int flat = (t + c * 256) * 4;
    int ii = flat >> 6, jj = flat & 63;
    float4 v = *(const float4*)(A + ((size_t)b * 512 + 256 + i0 + ii) * 512 + j0 + jj);
    T[ii][jj] = v.x; T[ii][jj + 1] = v.y; T[ii][jj + 2] = v.z; T[ii][jj + 3] = v.w;
  }
  __syncthreads();
  #pragma unroll
  for (int c = 0; c < 4; ++c) {
    int flat = (t + c * 256) * 4;
    int jj = flat >> 6, ii = flat & 63;
    float4 v = make_float4(T[ii][jj], T[ii + 1][jj], T[ii + 2][jj], T[ii + 3][jj]);
    *(float4*)(Atr + ((size_t)b * 512 + j0 + jj) * 256 + i0 + ii) = v;
  }
}

// ---------------- 4. per-round BP: grid = 3 rounds x 128 batches, A register-resident ----------------
__global__ __launch_bounds__(1024, 4) void k_bp(const float* __restrict__ Atr,
                                                const float* __restrict__ unary,
                                                const float* __restrict__ binc,
                                                const int* __restrict__ labels,
                                                float* __restrict__ out) {
  __shared__ float cbuf[256 * 8];   // c[j][0..4], stride 8 (b128-aligned)
  __shared__ float b3s[256 * 5];    // free-node beliefs
  __shared__ float msg[256 * 5];    // atomic combine; stride 5, gcd(5,32)=1 -> conflict-free
  __shared__ float binl[5 * 8];
  __shared__ int labs[256];
  int bid = blockIdx.x;
  int r = bid % 3, b = bid / 3;
  int t = threadIdx.x;
  int w = t >> 6, l = t & 63;
  int wh = w & 1, jc = w >> 1;      // i-half, j-chunk [32*jc, 32*jc+32)
  int i0 = wh * 128 + l;            // lane's i values: i0, i0+64
  if (t < 256) labs[t] = labels[b * 512 + t];
  if (t < 25) {
    float val;
    if (r == 0)      val = binc[b * 25 + t];
    else if (r == 1) val = out[PARKB + (size_t)b * 64 + t];
    else             val = out[PARKB + (size_t)b * 64 + 32 + t];
    binl[(t / 5) * 8 + (t % 5)] = val;
  }
  __syncthreads();
  // P1 (t<256): unary load (kept in regs), b0 = softmax(u), support-c into cbuf
  float u[5] = {};
  if (t < 256) {
    size_t ub = ((size_t)b * 512 + 256 + t) * 5;
    #pragma unroll
    for (int v = 0; v < 5; ++v) u[v] = unary[ub + v];
    float m = u[0];
    #pragma unroll
    for (int v = 1; v < 5; ++v) m = fmaxf(m, u[v]);
    float e[5], ssum = 0.f;
    #pragma unroll
    for (int v = 0; v < 5; ++v) { e[v] = expf(u[v] - m); ssum += e[v]; }
    float inv = 1.f / ssum;
    #pragma unroll
    for (int v = 0; v < 5; ++v) b3s[t * 5 + v] = e[v] * inv;
    int lab = labs[t];
    #pragma unroll
    for (int v = 0; v < 5; ++v) cbuf[t * 8 + v] = binl[lab * 8 + v];
  }
  __syncthreads();
  // P2: support partial (regs) + free-block A -> regs (held across all iterations)
  float asup[2][5] = {};
  float af[32][2];
  #pragma unroll
  for (int jj = 0; jj < 32; ++jj) {
    int j = jc * 32 + jj;
    float4 cq = *(const float4*)&cbuf[j * 8];
    float c4 = cbuf[j * 8 + 4];
    float ck[5] = {cq.x, cq.y, cq.z, cq.w, c4};
    size_t sbase = ((size_t)b * 512 + j) * 256 + i0;
    float a0 = Atr[sbase], a1 = Atr[sbase + 64];
    #pragma unroll
    for (int k = 0; k < 5; ++k) { asup[0][k] += a0 * ck[k]; asup[1][k] += a1 * ck[k]; }
    size_t fbase = ((size_t)b * 512 + 256 + j) * 256 + i0;
    af[jj][0] = Atr[fbase]; af[jj][1] = Atr[fbase + 64];
  }
  __syncthreads();
  for (int it = 0; it < BP_ITERS; ++it) {
    // A-phase (t<256): c[t] = b[t] @ binary ; zero ALL 1280 msg entries
    if (t < 256) {
      float bb[5];
      #pragma unroll
      for (int v = 0; v < 5; ++v) bb[v] = b3s[t * 5 + v];
      #pragma unroll
      for (int v = 0; v < 5; ++v) {
        float s = 0.f;
        #pragma unroll
        for (int ww = 0; ww < 5; ++ww) s += bb[ww] * binl[ww * 8 + v];
        cbuf[t * 8 + v] = s;
      }
    }
    msg[t] = 0.f;                         // t<1024 -> msg[0..1023]
    if (t < 256) msg[t + 1024] = 0.f;     // msg[1024..1279]
    __syncthreads();
    // B-phase: 16 waves, register A
    {
      float acc[2][5];
      #pragma unroll
      for (int g = 0; g < 2; ++g)
        #pragma unroll
        for (int k = 0; k < 5; ++k) acc[g][k] = asup[g][k];
      #pragma unroll
      for (int jj = 0; jj < 32; ++jj) {
        int j = jc * 32 + jj;
        float4 cq = *(const float4*)&cbuf[j * 8];
        float c4 = cbuf[j * 8 + 4];
        float ck[5] = {cq.x, cq.y, cq.z, cq.w, c4};
        #pragma unroll
        for (int k = 0; k < 5; ++k) {
          acc[0][k] += af[jj][0] * ck[k];
          acc[1][k] += af[jj][1] * ck[k];
        }
      }
      #pragma unroll
      for (int g = 0; g < 2; ++g)
        #pragma unroll
        for (int k = 0; k < 5; ++k) atomicAdd(&msg[(i0 + 64 * g) * 5 + k], acc[g][k]);
    }
    __syncthreads();
    // C-phase (t<256): b = softmax(u + msg)
    if (t < 256) {
      float lg[5];
      #pragma unroll
      for (int v = 0; v < 5; ++v) lg[v] = u[v] + msg[t * 5 + v];
      float m = lg[0];
      #pragma unroll
      for (int v = 1; v < 5; ++v) m = fmaxf(m, lg[v]);
      float e[5], ssum = 0.f;
      #pragma unroll
      for (int v = 0; v < 5; ++v) { e[v] = expf(lg[v] - m); ssum += e[v]; }
      float inv = 1.f / ssum;
      #pragma unroll
      for (int v = 0; v < 5; ++v) b3s[t * 5 + v] = e[v] * inv;
    }
    __syncthreads();
  }
  // P4 (t<512): write this round's clamped beliefs
  if (t < 512) {
    int n = t;
    float bel[5];
    if (n < 256) {
      int lab = labs[n];
      #pragma unroll
      for (int v = 0; v < 5; ++v) bel[v] = (v == lab) ? 1.f : 0.f;
    } else {
      #pragma unroll
      for (int v = 0; v < 5; ++v) bel[v] = b3s[(n - 256) * 5 + v];
    }
    size_t base = OFF_B1 + (size_t)r * 327680ull + ((size_t)b * 512 + n) * 5;
    #pragma unroll
    for (int v = 0; v < 5; ++v) out[base + v] = bel[v];
  }
}

// ---------------- 5. fused affinity pass (vectorized, non-temporal stores) ----------------
__global__ __launch_bounds__(256) void k_aff(const float* __restrict__ A, float* __restrict__ out) {
  __shared__ float belT[16][520];   // [k][j]: k=r*5+v (15 used), padded
  int bid = blockIdx.x;
  int b = bid >> 5, tile = bid & 31;
  int r0 = tile * 16;
  int t = threadIdx.x, w = t >> 6, l = t & 63;
  for (int idx = t; idx < 2560; idx += 256) {
    int j = idx / 5, v = idx % 5;
    belT[v][j]      = out[OFF_B1 + (size_t)b * 2560 + idx];
    belT[5 + v][j]  = out[OFF_B2 + (size_t)b * 2560 + idx];
    belT[10 + v][j] = out[OFF_B3 + (size_t)b * 2560 + idx];
  }
  __syncthreads();
  #pragma unroll 1
  for (int rr = 0; rr < 4; ++rr) {
    int row = r0 + w * 4 + rr;
    size_t base = ((size_t)b * 512 + row) * 512;
    float bi[15];
    #pragma unroll
    for (int k = 0; k < 15; ++k) bi[k] = belT[k][row];
    float4 a[2];
    float s1[2][4], s2[2][4], s3[2][4];
    float p1 = 0.f, p2 = 0.f, p3 = 0.f;
    #pragma unroll
    for (int g = 0; g < 2; ++g) {
      int c0 = g * 256 + l * 4;
      a[g] = *(const float4*)(A + base + c0);
      float4 bv[15];
      #pragma unroll
      for (int k = 0; k < 15; ++k) bv[k] = *(const float4*)&belT[k][c0];
      #pragma unroll
      for (int e = 0; e < 4; ++e) {
        float ae = ((const float*)&a[g])[e];
        float t1 = 0.f, t2 = 0.f, t3 = 0.f;
        #pragma unroll
        for (int v = 0; v < 5; ++v) {
          t1 += bi[v]      * ((const float*)&bv[v])[e];
          t2 += bi[5 + v]  * ((const float*)&bv[5 + v])[e];
          t3 += bi[10 + v] * ((const float*)&bv[10 + v])[e];
        }
        s1[g][e] = t1; s2[g][e] = t2; s3[g][e] = t3;
        p1 += ae * t1; p2 += ae * t2; p3 += ae * t3;
      }
    }
    #pragma unroll
    for (int off = 1; off < 64; off <<= 1) {
      p1 += __shfl_xor(p1, off, 64);
      p2 += __shfl_xor(p2, off, 64);
      p3 += __shfl_xor(p3, off, 64);
    }
    float inv1 = 1.f / (p1 + EPSF), inv2 = 1.f / (p2 + EPSF), inv3 = 1.f / (p3 + EPSF);
    #pragma unroll
    for (int g = 0; g < 2; ++g) {
      int c0 = g * 256 + l * 4;
      f32x4 av, o1, o2, o3;
      #pragma unroll
      for (int e = 0; e < 4; ++e) {
        float ae = ((const float*)&a[g])[e];
        av[e] = ae;
        o1[e] = ae * s1[g][e] * inv1;
        o2[e] = ae * s2[g][e] * inv2;
        o3[e] = ae * s3[g][e] * inv3;
      }
      __builtin_nontemporal_store(av, (f32x4*)(out + OFF_A   + base + c0));
      __builtin_nontemporal_store(o1, (f32x4*)(out + OFF_AF1 + base + c0));
      __builtin_nontemporal_store(o2, (f32x4*)(out + OFF_AF2 + base + c0));
      __builtin_nontemporal_store(o3, (f32x4*)(out + OFF_AF3 + base + c0));
    }
  }
}

extern "C" void kernel_launch(void* const* d_in, const int* in_sizes, int n_in,
                              void* d_out, int out_size, void* d_ws, size_t ws_size,
                              hipStream_t stream) {
  (void)in_sizes; (void)n_in; (void)out_size; (void)d_ws; (void)ws_size;
  const float* inp  = (const float*)d_in[0];
  const float* aff  = (const float*)d_in[1];
  const float* una  = (const float*)d_in[2];
  const float* binc = (const float*)d_in[3];
  const int*   lab  = (const int*)d_in[4];
  const float* W1 = (const float*)d_in[6];
  const float* b1 = (const float*)d_in[7];
  const float* W2 = (const float*)d_in[8];
  const float* b2 = (const float*)d_in[9];
  float* out = (float*)d_out;

  k_mgemm<64, false><<<512, 256, 0, stream>>>(inp, 65536, W1, 0, out + Y1_OFF, nullptr, 128);
  k_mgemm<64, true ><<<512, 256, 0, stream>>>(aff, 262144, out + Y1_OFF, 32768, out + X1_OFF, b1, 512);
  k_bc<64><<<128, 256, 0, stream>>>(out + X1_OFF, lab, out + PARKB, 0);
  k_mgemm<32, false><<<512, 256, 0, stream>>>(out + X1_OFF, 32768, W2, 0, out + Y2_OFF, nullptr, 64);
  k_mgemm<32, true ><<<512, 256, 0, stream>>>(aff, 262144, out + Y2_OFF, 16384, out + X2_OFF, b2, 512);
  k_bc<32><<<128, 256, 0, stream>>>(out + X2_OFF, lab, out + PARKB, 32);
  k_At<<<4096, 256, 0, stream>>>(aff, out + AT_OFF);
  k_bp<<<384, 1024, 0, stream>>>(out + AT_OFF, una, binc, lab, out);
  k_aff<<<4096, 256, 0, stream>>>(aff, out);
}